// Round 6
// baseline (734.010 us; speedup 1.0000x reference)
//
#include <hip/hip_runtime.h>
#include <hip/hip_bf16.h>

#define D_IN 128
#define D_EMB 64

// ---- weight prep: W[64][K] row-major -> Wt4[k4][j] = float4(W[j][4k4..4k4+3]) ----
__global__ __launch_bounds__(256) void wprep_k(const float4* __restrict__ W4,
                                               float4* __restrict__ out, int K4) {
  int idx = blockIdx.x * 256 + threadIdx.x;
  if (idx >= K4 * 64) return;
  int j = idx & 63, k4 = idx >> 6;
  out[idx] = W4[j * K4 + k4];
}

// ---- CSR build ----
__global__ __launch_bounds__(256) void degcnt_k(const int* __restrict__ dst,
                                                int* __restrict__ deg, int E) {
  int e = blockIdx.x * 256 + threadIdx.x;
  if (e < E) atomicAdd(deg + dst[e], 1);
}

__global__ __launch_bounds__(256) void invdeg_k(const int* __restrict__ deg,
                                                float* __restrict__ invdeg, int N) {
  int i = blockIdx.x * 256 + threadIdx.x;
  if (i < N) invdeg[i] = 1.0f / fmaxf((float)deg[i], 1.0f);
}

__global__ __launch_bounds__(256) void blocksum_k(const int* __restrict__ deg,
                                                  int* __restrict__ bsum) {
  __shared__ int sm[256];
  int t = threadIdx.x;
  sm[t] = deg[blockIdx.x * 256 + t];
  __syncthreads();
  for (int s = 128; s > 0; s >>= 1) {
    if (t < s) sm[t] += sm[t + s];
    __syncthreads();
  }
  if (t == 0) bsum[blockIdx.x] = sm[0];
}

// single block: exclusive scan of 512 block sums (in place)
__global__ __launch_bounds__(256) void scanbsum_k(int* __restrict__ bsum) {
  __shared__ int a[512], b[512];
  int t = threadIdx.x;
  a[t] = bsum[t];
  a[t + 256] = bsum[t + 256];
  __syncthreads();
  int* in = a;
  int* out = b;
  for (int st = 1; st < 512; st <<= 1) {
    for (int i = t; i < 512; i += 256) out[i] = in[i] + (i >= st ? in[i - st] : 0);
    __syncthreads();
    int* tmp = in; in = out; out = tmp;
  }
  for (int i = t; i < 512; i += 256) bsum[i] = (i == 0) ? 0 : in[i - 1];
}

// per-block inclusive scan of deg + block offset -> rowPtr (exclusive), cursor copy
__global__ __launch_bounds__(256) void rowptr_k(const int* __restrict__ deg,
                                                const int* __restrict__ bsumEx,
                                                int* __restrict__ rowPtr,
                                                int* __restrict__ cursor) {
  __shared__ int a[256], b[256];
  int t = threadIdx.x;
  int i = blockIdx.x * 256 + t;
  int d = deg[i];
  a[t] = d;
  __syncthreads();
  int* in = a;
  int* out = b;
  for (int st = 1; st < 256; st <<= 1) {
    out[t] = in[t] + (t >= st ? in[t - st] : 0);
    __syncthreads();
    int* tmp = in; in = out; out = tmp;
  }
  int incl = in[t] + bsumEx[blockIdx.x];
  rowPtr[i + 1] = incl;
  cursor[i] = incl - d;
  if (i == 0) rowPtr[0] = 0;
}

// ---- dst-partitioned CSR fill: 8 part-groups; group p commits only dst in
// [p*N/8,(p+1)*N/8). With round-robin block->XCD dispatch, each csr line is
// written by one XCD only -> no cross-XCD line ping-pong (round-5 fill_k showed
// 135 MB WRITE_SIZE for an 8 MB csr = 16x write amplification). Edge list is
// L3-resident so the 8x re-read is cheap. Correct under ANY block mapping.
__global__ __launch_bounds__(256) void fill_part_k(const int* __restrict__ src,
                                                   const int* __restrict__ dst,
                                                   int* __restrict__ cursor,
                                                   int* __restrict__ csr,
                                                   int E, int N) {
  const int part = blockIdx.x & 7;
  const int bid = blockIdx.x >> 3;
  const int nblk = gridDim.x >> 3;
  const int nlo = part * (N >> 3);
  const int nhi = nlo + (N >> 3);
  for (int e = bid * 256 + threadIdx.x; e < E; e += nblk * 256) {
    int d = dst[e];
    if (d >= nlo && d < nhi) {
      int p = atomicAdd(cursor + d, 1);
      csr[p] = src[e];
    }
  }
}

// ---- GEMM with LDS-staged x tile. 32 nodes/block, 4 waves x 8 nodes.
// out1 = bf16(x @ W1.T) ; DUAL: out2 = fp32(bias2 + x @ W2.T)
template <int K, int DUAL>
__global__ __launch_bounds__(256) void gemm_k(const float4* __restrict__ x4,
                                              const float4* __restrict__ wt1,
                                              const float4* __restrict__ wt2,
                                              const float* __restrict__ bias2,
                                              __hip_bfloat16* __restrict__ out1,
                                              float* __restrict__ out2) {
  constexpr int K4 = K / 4;
  __shared__ float4 sx[32 * K4];
  const int t = threadIdx.x;
  const int nb = blockIdx.x * 32;
#pragma unroll
  for (int idx = t; idx < 32 * K4; idx += 256) sx[idx] = x4[(size_t)nb * K4 + idx];
  __syncthreads();
  const int j = t & 63;
  const int wv = t >> 6;
  const int r0 = wv * 8;
  float acc1[8], acc2[8];
  const float bj = DUAL ? bias2[j] : 0.0f;
#pragma unroll
  for (int i = 0; i < 8; i++) { acc1[i] = 0.0f; acc2[i] = bj; }
  for (int k4 = 0; k4 < K4; k4++) {
    float4 w1 = wt1[k4 * 64 + j];
    float4 w2;
    if (DUAL) w2 = wt2[k4 * 64 + j];
#pragma unroll
    for (int i = 0; i < 8; i++) {
      float4 xv = sx[(r0 + i) * K4 + k4];   // broadcast ds_read_b128
      acc1[i] += xv.x * w1.x + xv.y * w1.y + xv.z * w1.z + xv.w * w1.w;
      if (DUAL)
        acc2[i] += xv.x * w2.x + xv.y * w2.y + xv.z * w2.z + xv.w * w2.w;
    }
  }
#pragma unroll
  for (int i = 0; i < 8; i++) {
    out1[(size_t)(nb + r0 + i) * 64 + j] = __float2bfloat16(acc1[i]);
    if (DUAL) out2[(size_t)(nb + r0 + i) * 64 + j] = acc2[i];
  }
}

// ---- gather aggregation over bf16 messages, fused graph-mean accumulation ----
// wave per node (4 nodes/wave), 8 lanes x uint4 (8 bf16, 16 B) per edge row (128 B),
// 8 edges in flight per wave. Edge ids read directly (csr[e], HW broadcast across
// the 8 lanes of a group) — NO shfl of edge ids (undefined from exited lanes;
// caused the round-2/4 failures).
// WRITE_H=1: hio[n] = sum*invdeg + hio[n] (in-place fp32), gmean += h/2048
// WRITE_H=0: gmean += (sum*invdeg)/2048  (h2 never materialized)
template <int WRITE_H>
__global__ __launch_bounds__(256) void gather_k(const uint4* __restrict__ yb,
                                                const int* __restrict__ csr,
                                                const int* __restrict__ rowPtr,
                                                const float* __restrict__ invdeg,
                                                float4* __restrict__ hio,
                                                float* __restrict__ gmean) {
  __shared__ float sg[4][8][8];
  const int t = threadIdx.x;
  const int lane = t & 63;
  const int wv = t >> 6;
  const int c = lane & 7;    // which uint4 (8 bf16) of the 64-elem row
  const int eg = lane >> 3;  // edge group 0..7
  const int nb = blockIdx.x * 16;  // 16 consecutive nodes/block (2048%16==0 -> same graph)
  float gacc[8];
#pragma unroll
  for (int k = 0; k < 8; k++) gacc[k] = 0.0f;
  for (int i = 0; i < 4; i++) {
    int n = nb + wv * 4 + i;
    int base = rowPtr[n], end = rowPtr[n + 1];
    float acc[8];
#pragma unroll
    for (int k = 0; k < 8; k++) acc[k] = 0.0f;
    for (int e = base + eg; e < end; e += 8) {
      int s = csr[e];
      uint4 v = yb[(size_t)s * 8 + c];
      acc[0] += __uint_as_float(v.x << 16);
      acc[1] += __uint_as_float(v.x & 0xffff0000u);
      acc[2] += __uint_as_float(v.y << 16);
      acc[3] += __uint_as_float(v.y & 0xffff0000u);
      acc[4] += __uint_as_float(v.z << 16);
      acc[5] += __uint_as_float(v.z & 0xffff0000u);
      acc[6] += __uint_as_float(v.w << 16);
      acc[7] += __uint_as_float(v.w & 0xffff0000u);
    }
#pragma unroll
    for (int m = 8; m <= 32; m <<= 1)
#pragma unroll
      for (int k = 0; k < 8; k++) acc[k] += __shfl_xor(acc[k], m, 64);
    if (eg == 0) {
      float sc = invdeg[n];
      if (WRITE_H) {
        float4 o1 = hio[(size_t)n * 16 + 2 * c];
        float4 o2 = hio[(size_t)n * 16 + 2 * c + 1];
        float4 h1 = make_float4(acc[0] * sc + o1.x, acc[1] * sc + o1.y,
                                acc[2] * sc + o1.z, acc[3] * sc + o1.w);
        float4 h2 = make_float4(acc[4] * sc + o2.x, acc[5] * sc + o2.y,
                                acc[6] * sc + o2.z, acc[7] * sc + o2.w);
        hio[(size_t)n * 16 + 2 * c] = h1;
        hio[(size_t)n * 16 + 2 * c + 1] = h2;
        gacc[0] += h1.x; gacc[1] += h1.y; gacc[2] += h1.z; gacc[3] += h1.w;
        gacc[4] += h2.x; gacc[5] += h2.y; gacc[6] += h2.z; gacc[7] += h2.w;
      } else {
#pragma unroll
        for (int k = 0; k < 8; k++) gacc[k] += acc[k] * sc;
      }
    }
  }
  if (eg == 0) {
#pragma unroll
    for (int k = 0; k < 8; k++) sg[wv][c][k] = gacc[k];
  }
  __syncthreads();
  if (wv == 0 && eg == 0) {
    const float s = 1.0f / 2048.0f;
    int graph = nb >> 11;
    float* gp = gmean + graph * 64 + c * 8;
#pragma unroll
    for (int k = 0; k < 8; k++) {
      float tot = sg[0][c][k] + sg[1][c][k] + sg[2][c][k] + sg[3][c][k];
      atomicAdd(gp + k, tot * s);
    }
  }
}

// ---- g[b][j] = gmean2[b][j] + b2l[j] + sum_k gmean1[b][k] * W2r[j][k] ----
__global__ __launch_bounds__(256) void combine_k(const float* __restrict__ gmean2,
                                                 const float* __restrict__ gmean1,
                                                 const float* __restrict__ b2l,
                                                 const float* __restrict__ W2r,
                                                 float* __restrict__ g) {
  int idx = blockIdx.x * 256 + threadIdx.x;   // 4096
  int b = idx >> 6, j = idx & 63;
  const float4* m4 = (const float4*)(gmean1 + b * 64);
  const float4* w4 = (const float4*)(W2r + j * 64);
  float acc = gmean2[idx] + b2l[j];
#pragma unroll
  for (int k4 = 0; k4 < 16; k4++) {
    float4 mv = m4[k4], wv = w4[k4];
    acc += mv.x * wv.x + mv.y * wv.y + mv.z * wv.z + mv.w * wv.w;
  }
  g[idx] = acc;
}

// ---- h = relu(g @ fc1_W.T + fc1_b)   g:[64,64] fc1_W:[128,64] -> h:[64,128] ----
__global__ __launch_bounds__(256) void mlp1_k(const float* __restrict__ g,
                                              const float* __restrict__ fc1_W,
                                              const float* __restrict__ fc1_b,
                                              float* __restrict__ h) {
  int idx = blockIdx.x * 256 + threadIdx.x;
  int b = idx >> 7, k = idx & 127;
  const float4* g4 = (const float4*)(g + b * 64);
  const float4* w4 = (const float4*)(fc1_W + k * 64);
  float acc = fc1_b[k];
#pragma unroll
  for (int j4 = 0; j4 < 16; j4++) {
    float4 gv = g4[j4], wv = w4[j4];
    acc += gv.x * wv.x + gv.y * wv.y + gv.z * wv.z + gv.w * wv.w;
  }
  h[idx] = fmaxf(acc, 0.0f);
}

// ---- q = h @ fc2_W.T + fc2_b   h:[64,128] fc2_W:[2048,128] -> q:[64,2048] ----
__global__ __launch_bounds__(256) void mlp2_k(const float* __restrict__ h,
                                              const float* __restrict__ fc2_W,
                                              const float* __restrict__ fc2_b,
                                              float* __restrict__ out) {
  __shared__ float4 sh[32];
  int b = blockIdx.x >> 3;
  int a = (blockIdx.x & 7) * 256 + threadIdx.x;
  if (threadIdx.x < 32) sh[threadIdx.x] = ((const float4*)(h + b * 128))[threadIdx.x];
  __syncthreads();
  const float4* w4 = (const float4*)(fc2_W + (size_t)a * 128);
  float acc = fc2_b[a];
#pragma unroll
  for (int k4 = 0; k4 < 32; k4++) {
    float4 hv = sh[k4], wv = w4[k4];
    acc += hv.x * wv.x + hv.y * wv.y + hv.z * wv.z + hv.w * wv.w;
  }
  out[b * 2048 + a] = acc;
}

extern "C" void kernel_launch(void* const* d_in, const int* in_sizes, int n_in,
                              void* d_out, int out_size, void* d_ws, size_t ws_size,
                              hipStream_t stream) {
  const float* x     = (const float*)d_in[0];
  const int*   ei    = (const int*)d_in[1];
  const float* W1l   = (const float*)d_in[2];
  const float* b1l   = (const float*)d_in[3];
  const float* W1r   = (const float*)d_in[4];
  const float* W2l   = (const float*)d_in[5];
  const float* b2l   = (const float*)d_in[6];
  const float* W2r   = (const float*)d_in[7];
  const float* fc1_W = (const float*)d_in[8];
  const float* fc1_b = (const float*)d_in[9];
  const float* fc2_W = (const float*)d_in[10];
  const float* fc2_b = (const float*)d_in[11];
  float* out = (float*)d_out;

  const int N = in_sizes[0] / D_IN;   // 131072
  const int E = in_sizes[1] / 2;      // 2097152
  const int* src = ei;
  const int* dst = ei + E;

  // workspace layout (~59 MiB total; 78 MiB proven available in round 3)
  char* ws = (char*)d_ws;
  int*   deg    = (int*)ws;     ws += (size_t)N * 4;
  int*   cursor = (int*)ws;     ws += (size_t)N * 4;
  int*   rowPtr = (int*)ws;     ws += (size_t)(N + 256) * 4;
  int*   bsum   = (int*)ws;     ws += 512 * 4;
  float* invdeg = (float*)ws;   ws += (size_t)N * 4;
  float* gmean1 = (float*)ws;   ws += 4096 * 4;
  float* gmean2 = (float*)ws;   ws += 4096 * 4;
  float* g      = (float*)ws;   ws += 4096 * 4;
  float* hbuf   = (float*)ws;   ws += 8192 * 4;
  float* wt1l   = (float*)ws;   ws += 8192 * 4;
  float* wt1r   = (float*)ws;   ws += 8192 * 4;
  float* wt2l   = (float*)ws;   ws += 4096 * 4;
  int*   csr    = (int*)ws;     ws += (size_t)E * 4;
  __hip_bfloat16* bufA = (__hip_bfloat16*)ws;  ws += (size_t)64 * N * 2;  // y1/y2 bf16
  float* bufB   = (float*)ws;   ws += (size_t)64 * N * 4;  // xr -> h1 (in place, fp32)

  hipMemsetAsync(deg, 0, (size_t)N * 4, stream);
  hipMemsetAsync(gmean1, 0, 2 * 4096 * 4, stream);   // gmean1 + gmean2 contiguous

  wprep_k<<<8, 256, 0, stream>>>((const float4*)W1l, (float4*)wt1l, 32);
  wprep_k<<<8, 256, 0, stream>>>((const float4*)W1r, (float4*)wt1r, 32);
  wprep_k<<<4, 256, 0, stream>>>((const float4*)W2l, (float4*)wt2l, 16);

  // CSR build (reused by both convs)
  degcnt_k<<<(E + 255) / 256, 256, 0, stream>>>(dst, deg, E);
  invdeg_k<<<(N + 255) / 256, 256, 0, stream>>>(deg, invdeg, N);
  blocksum_k<<<N / 256, 256, 0, stream>>>(deg, bsum);
  scanbsum_k<<<1, 256, 0, stream>>>(bsum);
  rowptr_k<<<N / 256, 256, 0, stream>>>(deg, bsum, rowPtr, cursor);
  fill_part_k<<<1024, 256, 0, stream>>>(src, dst, cursor, csr, E, N);

  // conv1: y1 = bf16(x@W1l.T) -> bufA ; xr = b1l + x@W1r.T -> bufB (fp32)
  gemm_k<128, 1><<<N / 32, 256, 0, stream>>>((const float4*)x, (const float4*)wt1l,
                                             (const float4*)wt1r, b1l, bufA, bufB);
  // h1 = gather(y1)*invdeg + xr -> bufB in place; gmean1 += h1/2048
  gather_k<1><<<N / 16, 256, 0, stream>>>((const uint4*)bufA, csr, rowPtr, invdeg,
                                          (float4*)bufB, gmean1);

  // conv2: y2 = bf16(h1@W2l.T) -> bufA
  gemm_k<64, 0><<<N / 32, 256, 0, stream>>>((const float4*)bufB, (const float4*)wt2l,
                                            nullptr, nullptr, bufA, nullptr);
  // gmean2 += gather(y2)*invdeg / 2048  (h2 never materialized)
  gather_k<0><<<N / 16, 256, 0, stream>>>((const uint4*)bufA, csr, rowPtr, invdeg,
                                          nullptr, gmean2);

  // g = gmean2 + b2l + gmean1 @ W2r.T
  combine_k<<<16, 256, 0, stream>>>(gmean2, gmean1, b2l, W2r, g);
  mlp1_k<<<32, 256, 0, stream>>>(g, fc1_W, fc1_b, hbuf);
  mlp2_k<<<512, 256, 0, stream>>>(hbuf, fc2_W, fc2_b, out);
}

// Round 7
// 733.041 us; speedup vs baseline: 1.0013x; 1.0013x over previous
//
#include <hip/hip_runtime.h>
#include <hip/hip_bf16.h>

#define D_IN 128
#define D_EMB 64

typedef float f32x2 __attribute__((ext_vector_type(2)));

// ---- weight prep: W[64][K] row-major -> Wt4[k4][j] = float4(W[j][4k4..4k4+3]) ----
__global__ __launch_bounds__(256) void wprep_k(const float4* __restrict__ W4,
                                               float4* __restrict__ out, int K4) {
  int idx = blockIdx.x * 256 + threadIdx.x;
  if (idx >= K4 * 64) return;
  int j = idx & 63, k4 = idx >> 6;
  out[idx] = W4[j * K4 + k4];
}

// ---- CSR build ----
__global__ __launch_bounds__(256) void degcnt_k(const int* __restrict__ dst,
                                                int* __restrict__ deg, int E) {
  int e = blockIdx.x * 256 + threadIdx.x;
  if (e < E) atomicAdd(deg + dst[e], 1);
}

__global__ __launch_bounds__(256) void invdeg_k(const int* __restrict__ deg,
                                                float* __restrict__ invdeg, int N) {
  int i = blockIdx.x * 256 + threadIdx.x;
  if (i < N) invdeg[i] = 1.0f / fmaxf((float)deg[i], 1.0f);
}

__global__ __launch_bounds__(256) void blocksum_k(const int* __restrict__ deg,
                                                  int* __restrict__ bsum) {
  __shared__ int sm[256];
  int t = threadIdx.x;
  sm[t] = deg[blockIdx.x * 256 + t];
  __syncthreads();
  for (int s = 128; s > 0; s >>= 1) {
    if (t < s) sm[t] += sm[t + s];
    __syncthreads();
  }
  if (t == 0) bsum[blockIdx.x] = sm[0];
}

// single block: exclusive scan of 512 block sums (in place)
__global__ __launch_bounds__(256) void scanbsum_k(int* __restrict__ bsum) {
  __shared__ int a[512], b[512];
  int t = threadIdx.x;
  a[t] = bsum[t];
  a[t + 256] = bsum[t + 256];
  __syncthreads();
  int* in = a;
  int* out = b;
  for (int st = 1; st < 512; st <<= 1) {
    for (int i = t; i < 512; i += 256) out[i] = in[i] + (i >= st ? in[i - st] : 0);
    __syncthreads();
    int* tmp = in; in = out; out = tmp;
  }
  for (int i = t; i < 512; i += 256) bsum[i] = (i == 0) ? 0 : in[i - 1];
}

// per-block inclusive scan of deg + block offset -> rowPtr (exclusive), cursor copy
__global__ __launch_bounds__(256) void rowptr_k(const int* __restrict__ deg,
                                                const int* __restrict__ bsumEx,
                                                int* __restrict__ rowPtr,
                                                int* __restrict__ cursor) {
  __shared__ int a[256], b[256];
  int t = threadIdx.x;
  int i = blockIdx.x * 256 + t;
  int d = deg[i];
  a[t] = d;
  __syncthreads();
  int* in = a;
  int* out = b;
  for (int st = 1; st < 256; st <<= 1) {
    out[t] = in[t] + (t >= st ? in[t - st] : 0);
    __syncthreads();
    int* tmp = in; in = out; out = tmp;
  }
  int incl = in[t] + bsumEx[blockIdx.x];
  rowPtr[i + 1] = incl;
  cursor[i] = incl - d;
  if (i == 0) rowPtr[0] = 0;
}

// ---- dst-partitioned CSR fill (8 part-groups; kills cross-XCD csr line thrash) ----
__global__ __launch_bounds__(256) void fill_part_k(const int* __restrict__ src,
                                                   const int* __restrict__ dst,
                                                   int* __restrict__ cursor,
                                                   int* __restrict__ csr,
                                                   int E, int N) {
  const int part = blockIdx.x & 7;
  const int bid = blockIdx.x >> 3;
  const int nblk = gridDim.x >> 3;
  const int nlo = part * (N >> 3);
  const int nhi = nlo + (N >> 3);
  for (int e = bid * 256 + threadIdx.x; e < E; e += nblk * 256) {
    int d = dst[e];
    if (d >= nlo && d < nhi) {
      int p = atomicAdd(cursor + d, 1);
      csr[p] = src[e];
    }
  }
}

// ---- GEMM with LDS-staged x tile. 32 nodes/block, 4 waves x 8 nodes.
// out1 = fp8_e4m3(x @ W1.T) ; DUAL: out2 = fp32(bias2 + x @ W2.T)
template <int K, int DUAL>
__global__ __launch_bounds__(256) void gemm_k(const float4* __restrict__ x4,
                                              const float4* __restrict__ wt1,
                                              const float4* __restrict__ wt2,
                                              const float* __restrict__ bias2,
                                              unsigned char* __restrict__ out1,
                                              float* __restrict__ out2) {
  constexpr int K4 = K / 4;
  __shared__ float4 sx[32 * K4];
  const int t = threadIdx.x;
  const int nb = blockIdx.x * 32;
#pragma unroll
  for (int idx = t; idx < 32 * K4; idx += 256) sx[idx] = x4[(size_t)nb * K4 + idx];
  __syncthreads();
  const int j = t & 63;
  const int wv = t >> 6;
  const int r0 = wv * 8;
  float acc1[8], acc2[8];
  const float bj = DUAL ? bias2[j] : 0.0f;
#pragma unroll
  for (int i = 0; i < 8; i++) { acc1[i] = 0.0f; acc2[i] = bj; }
  for (int k4 = 0; k4 < K4; k4++) {
    float4 w1 = wt1[k4 * 64 + j];
    float4 w2;
    if (DUAL) w2 = wt2[k4 * 64 + j];
#pragma unroll
    for (int i = 0; i < 8; i++) {
      float4 xv = sx[(r0 + i) * K4 + k4];   // broadcast ds_read_b128
      acc1[i] += xv.x * w1.x + xv.y * w1.y + xv.z * w1.z + xv.w * w1.w;
      if (DUAL)
        acc2[i] += xv.x * w2.x + xv.y * w2.y + xv.z * w2.z + xv.w * w2.w;
    }
  }
#pragma unroll
  for (int i = 0; i < 8; i++) {
    // OCP e4m3 encode (gfx950 v_cvt_pk_fp8_f32, RNE, saturating)
    unsigned pk = (unsigned)__builtin_amdgcn_cvt_pk_fp8_f32(acc1[i], acc1[i], 0, false);
    out1[(size_t)(nb + r0 + i) * 64 + j] = (unsigned char)(pk & 0xff);
    if (DUAL) out2[(size_t)(nb + r0 + i) * 64 + j] = acc2[i];
  }
}

// ---- gather aggregation over fp8 messages, fused graph-mean accumulation ----
// wave per node (4 nodes/wave), 8 lanes x uint2 (8 fp8, 8 B) per edge row (64 B =
// ONE cache line per edge), 8 edges in flight per wave. Edge ids read directly
// (csr[e], HW broadcast) — NO shfl of edge ids (undefined from exited lanes).
// WRITE_H=1: hio[n] = sum*invdeg + hio[n] (in-place fp32), gmean += h/2048
// WRITE_H=0: gmean += (sum*invdeg)/2048  (h2 never materialized)
template <int WRITE_H>
__global__ __launch_bounds__(256) void gather_k(const uint2* __restrict__ yb,
                                                const int* __restrict__ csr,
                                                const int* __restrict__ rowPtr,
                                                const float* __restrict__ invdeg,
                                                float4* __restrict__ hio,
                                                float* __restrict__ gmean) {
  __shared__ float sg[4][8][8];
  const int t = threadIdx.x;
  const int lane = t & 63;
  const int wv = t >> 6;
  const int c = lane & 7;    // which 8-fp8 chunk of the 64-elem row
  const int eg = lane >> 3;  // edge group 0..7
  const int nb = blockIdx.x * 16;  // 16 consecutive nodes/block (2048%16==0 -> same graph)
  float gacc[8];
#pragma unroll
  for (int k = 0; k < 8; k++) gacc[k] = 0.0f;
  for (int i = 0; i < 4; i++) {
    int n = nb + wv * 4 + i;
    int base = rowPtr[n], end = rowPtr[n + 1];
    float acc[8];
#pragma unroll
    for (int k = 0; k < 8; k++) acc[k] = 0.0f;
    for (int e = base + eg; e < end; e += 8) {
      int s = csr[e];
      uint2 v = yb[(size_t)s * 8 + c];
      f32x2 p0 = __builtin_amdgcn_cvt_pk_f32_fp8(v.x, false);
      f32x2 p1 = __builtin_amdgcn_cvt_pk_f32_fp8(v.x, true);
      f32x2 p2 = __builtin_amdgcn_cvt_pk_f32_fp8(v.y, false);
      f32x2 p3 = __builtin_amdgcn_cvt_pk_f32_fp8(v.y, true);
      acc[0] += p0.x; acc[1] += p0.y;
      acc[2] += p1.x; acc[3] += p1.y;
      acc[4] += p2.x; acc[5] += p2.y;
      acc[6] += p3.x; acc[7] += p3.y;
    }
#pragma unroll
    for (int m = 8; m <= 32; m <<= 1)
#pragma unroll
      for (int k = 0; k < 8; k++) acc[k] += __shfl_xor(acc[k], m, 64);
    if (eg == 0) {
      float sc = invdeg[n];
      if (WRITE_H) {
        float4 o1 = hio[(size_t)n * 16 + 2 * c];
        float4 o2 = hio[(size_t)n * 16 + 2 * c + 1];
        float4 h1 = make_float4(acc[0] * sc + o1.x, acc[1] * sc + o1.y,
                                acc[2] * sc + o1.z, acc[3] * sc + o1.w);
        float4 h2 = make_float4(acc[4] * sc + o2.x, acc[5] * sc + o2.y,
                                acc[6] * sc + o2.z, acc[7] * sc + o2.w);
        hio[(size_t)n * 16 + 2 * c] = h1;
        hio[(size_t)n * 16 + 2 * c + 1] = h2;
        gacc[0] += h1.x; gacc[1] += h1.y; gacc[2] += h1.z; gacc[3] += h1.w;
        gacc[4] += h2.x; gacc[5] += h2.y; gacc[6] += h2.z; gacc[7] += h2.w;
      } else {
#pragma unroll
        for (int k = 0; k < 8; k++) gacc[k] += acc[k] * sc;
      }
    }
  }
  if (eg == 0) {
#pragma unroll
    for (int k = 0; k < 8; k++) sg[wv][c][k] = gacc[k];
  }
  __syncthreads();
  if (wv == 0 && eg == 0) {
    const float s = 1.0f / 2048.0f;
    int graph = nb >> 11;
    float* gp = gmean + graph * 64 + c * 8;
#pragma unroll
    for (int k = 0; k < 8; k++) {
      float tot = sg[0][c][k] + sg[1][c][k] + sg[2][c][k] + sg[3][c][k];
      atomicAdd(gp + k, tot * s);
    }
  }
}

// ---- g[b][j] = gmean2[b][j] + b2l[j] + sum_k gmean1[b][k] * W2r[j][k] ----
__global__ __launch_bounds__(256) void combine_k(const float* __restrict__ gmean2,
                                                 const float* __restrict__ gmean1,
                                                 const float* __restrict__ b2l,
                                                 const float* __restrict__ W2r,
                                                 float* __restrict__ g) {
  int idx = blockIdx.x * 256 + threadIdx.x;   // 4096
  int b = idx >> 6, j = idx & 63;
  const float4* m4 = (const float4*)(gmean1 + b * 64);
  const float4* w4 = (const float4*)(W2r + j * 64);
  float acc = gmean2[idx] + b2l[j];
#pragma unroll
  for (int k4 = 0; k4 < 16; k4++) {
    float4 mv = m4[k4], wv = w4[k4];
    acc += mv.x * wv.x + mv.y * wv.y + mv.z * wv.z + mv.w * wv.w;
  }
  g[idx] = acc;
}

// ---- h = relu(g @ fc1_W.T + fc1_b)   g:[64,64] fc1_W:[128,64] -> h:[64,128] ----
__global__ __launch_bounds__(256) void mlp1_k(const float* __restrict__ g,
                                              const float* __restrict__ fc1_W,
                                              const float* __restrict__ fc1_b,
                                              float* __restrict__ h) {
  int idx = blockIdx.x * 256 + threadIdx.x;
  int b = idx >> 7, k = idx & 127;
  const float4* g4 = (const float4*)(g + b * 64);
  const float4* w4 = (const float4*)(fc1_W + k * 64);
  float acc = fc1_b[k];
#pragma unroll
  for (int j4 = 0; j4 < 16; j4++) {
    float4 gv = g4[j4], wv = w4[j4];
    acc += gv.x * wv.x + gv.y * wv.y + gv.z * wv.z + gv.w * wv.w;
  }
  h[idx] = fmaxf(acc, 0.0f);
}

// ---- q = h @ fc2_W.T + fc2_b   h:[64,128] fc2_W:[2048,128] -> q:[64,2048] ----
__global__ __launch_bounds__(256) void mlp2_k(const float* __restrict__ h,
                                              const float* __restrict__ fc2_W,
                                              const float* __restrict__ fc2_b,
                                              float* __restrict__ out) {
  __shared__ float4 sh[32];
  int b = blockIdx.x >> 3;
  int a = (blockIdx.x & 7) * 256 + threadIdx.x;
  if (threadIdx.x < 32) sh[threadIdx.x] = ((const float4*)(h + b * 128))[threadIdx.x];
  __syncthreads();
  const float4* w4 = (const float4*)(fc2_W + (size_t)a * 128);
  float acc = fc2_b[a];
#pragma unroll
  for (int k4 = 0; k4 < 32; k4++) {
    float4 hv = sh[k4], wv = w4[k4];
    acc += hv.x * wv.x + hv.y * wv.y + hv.z * wv.z + hv.w * wv.w;
  }
  out[b * 2048 + a] = acc;
}

extern "C" void kernel_launch(void* const* d_in, const int* in_sizes, int n_in,
                              void* d_out, int out_size, void* d_ws, size_t ws_size,
                              hipStream_t stream) {
  const float* x     = (const float*)d_in[0];
  const int*   ei    = (const int*)d_in[1];
  const float* W1l   = (const float*)d_in[2];
  const float* b1l   = (const float*)d_in[3];
  const float* W1r   = (const float*)d_in[4];
  const float* W2l   = (const float*)d_in[5];
  const float* b2l   = (const float*)d_in[6];
  const float* W2r   = (const float*)d_in[7];
  const float* fc1_W = (const float*)d_in[8];
  const float* fc1_b = (const float*)d_in[9];
  const float* fc2_W = (const float*)d_in[10];
  const float* fc2_b = (const float*)d_in[11];
  float* out = (float*)d_out;

  const int N = in_sizes[0] / D_IN;   // 131072
  const int E = in_sizes[1] / 2;      // 2097152
  const int* src = ei;
  const int* dst = ei + E;

  // workspace layout (~52 MiB total; 78 MiB proven available in round 3)
  char* ws = (char*)d_ws;
  int*   deg    = (int*)ws;     ws += (size_t)N * 4;
  int*   cursor = (int*)ws;     ws += (size_t)N * 4;
  int*   rowPtr = (int*)ws;     ws += (size_t)(N + 256) * 4;
  int*   bsum   = (int*)ws;     ws += 512 * 4;
  float* invdeg = (float*)ws;   ws += (size_t)N * 4;
  float* gmean1 = (float*)ws;   ws += 4096 * 4;
  float* gmean2 = (float*)ws;   ws += 4096 * 4;
  float* g      = (float*)ws;   ws += 4096 * 4;
  float* hbuf   = (float*)ws;   ws += 8192 * 4;
  float* wt1l   = (float*)ws;   ws += 8192 * 4;
  float* wt1r   = (float*)ws;   ws += 8192 * 4;
  float* wt2l   = (float*)ws;   ws += 4096 * 4;
  int*   csr    = (int*)ws;     ws += (size_t)E * 4;
  unsigned char* bufA = (unsigned char*)ws;  ws += (size_t)64 * N;      // y1/y2 fp8
  float* bufB   = (float*)ws;   ws += (size_t)64 * N * 4;  // xr -> h1 (in place, fp32)

  hipMemsetAsync(deg, 0, (size_t)N * 4, stream);
  hipMemsetAsync(gmean1, 0, 2 * 4096 * 4, stream);   // gmean1 + gmean2 contiguous

  wprep_k<<<8, 256, 0, stream>>>((const float4*)W1l, (float4*)wt1l, 32);
  wprep_k<<<8, 256, 0, stream>>>((const float4*)W1r, (float4*)wt1r, 32);
  wprep_k<<<4, 256, 0, stream>>>((const float4*)W2l, (float4*)wt2l, 16);

  // CSR build (reused by both convs)
  degcnt_k<<<(E + 255) / 256, 256, 0, stream>>>(dst, deg, E);
  invdeg_k<<<(N + 255) / 256, 256, 0, stream>>>(deg, invdeg, N);
  blocksum_k<<<N / 256, 256, 0, stream>>>(deg, bsum);
  scanbsum_k<<<1, 256, 0, stream>>>(bsum);
  rowptr_k<<<N / 256, 256, 0, stream>>>(deg, bsum, rowPtr, cursor);
  fill_part_k<<<1024, 256, 0, stream>>>(src, dst, cursor, csr, E, N);

  // conv1: y1 = fp8(x@W1l.T) -> bufA ; xr = b1l + x@W1r.T -> bufB (fp32)
  gemm_k<128, 1><<<N / 32, 256, 0, stream>>>((const float4*)x, (const float4*)wt1l,
                                             (const float4*)wt1r, b1l, bufA, bufB);
  // h1 = gather(y1)*invdeg + xr -> bufB in place; gmean1 += h1/2048
  gather_k<1><<<N / 16, 256, 0, stream>>>((const uint2*)bufA, csr, rowPtr, invdeg,
                                          (float4*)bufB, gmean1);

  // conv2: y2 = fp8(h1@W2l.T) -> bufA
  gemm_k<64, 0><<<N / 32, 256, 0, stream>>>((const float4*)bufB, (const float4*)wt2l,
                                            nullptr, nullptr, bufA, nullptr);
  // gmean2 += gather(y2)*invdeg / 2048  (h2 never materialized)
  gather_k<0><<<N / 16, 256, 0, stream>>>((const uint2*)bufA, csr, rowPtr, invdeg,
                                          nullptr, gmean2);

  // g = gmean2 + b2l + gmean1 @ W2r.T
  combine_k<<<16, 256, 0, stream>>>(gmean2, gmean1, b2l, W2r, g);
  mlp1_k<<<32, 256, 0, stream>>>(g, fc1_W, fc1_b, hbuf);
  mlp2_k<<<512, 256, 0, stream>>>(hbuf, fc2_W, fc2_b, out);
}

// Round 8
// 620.873 us; speedup vs baseline: 1.1822x; 1.1807x over previous
//
#include <hip/hip_runtime.h>
#include <hip/hip_bf16.h>

#define D_IN 128
#define D_EMB 64

typedef float f32x2 __attribute__((ext_vector_type(2)));

// ---- weight prep: W[64][K] row-major -> Wt4[k4][j] = float4(W[j][4k4..4k4+3]) ----
__global__ __launch_bounds__(256) void wprep_k(const float4* __restrict__ W4,
                                               float4* __restrict__ out, int K4) {
  int idx = blockIdx.x * 256 + threadIdx.x;
  if (idx >= K4 * 64) return;
  int j = idx & 63, k4 = idx >> 6;
  out[idx] = W4[j * K4 + k4];
}

// ---- CSR build ----
// dst-partitioned degree count (same cross-XCD line-thrash fix as fill_part_k)
__global__ __launch_bounds__(256) void degcnt_part_k(const int* __restrict__ dst,
                                                     int* __restrict__ deg,
                                                     int E, int N) {
  const int part = blockIdx.x & 7;
  const int bid = blockIdx.x >> 3;
  const int nblk = gridDim.x >> 3;
  const int nlo = part * (N >> 3), nhi = nlo + (N >> 3);
  for (int e = bid * 256 + threadIdx.x; e < E; e += nblk * 256) {
    int d = dst[e];
    if (d >= nlo && d < nhi) atomicAdd(deg + d, 1);
  }
}

__global__ __launch_bounds__(256) void invdeg_k(const int* __restrict__ deg,
                                                float* __restrict__ invdeg, int N) {
  int i = blockIdx.x * 256 + threadIdx.x;
  if (i < N) invdeg[i] = 1.0f / fmaxf((float)deg[i], 1.0f);
}

__global__ __launch_bounds__(256) void blocksum_k(const int* __restrict__ deg,
                                                  int* __restrict__ bsum) {
  __shared__ int sm[256];
  int t = threadIdx.x;
  sm[t] = deg[blockIdx.x * 256 + t];
  __syncthreads();
  for (int s = 128; s > 0; s >>= 1) {
    if (t < s) sm[t] += sm[t + s];
    __syncthreads();
  }
  if (t == 0) bsum[blockIdx.x] = sm[0];
}

// single block: exclusive scan of 512 block sums (in place)
__global__ __launch_bounds__(256) void scanbsum_k(int* __restrict__ bsum) {
  __shared__ int a[512], b[512];
  int t = threadIdx.x;
  a[t] = bsum[t];
  a[t + 256] = bsum[t + 256];
  __syncthreads();
  int* in = a;
  int* out = b;
  for (int st = 1; st < 512; st <<= 1) {
    for (int i = t; i < 512; i += 256) out[i] = in[i] + (i >= st ? in[i - st] : 0);
    __syncthreads();
    int* tmp = in; in = out; out = tmp;
  }
  for (int i = t; i < 512; i += 256) bsum[i] = (i == 0) ? 0 : in[i - 1];
}

// per-block inclusive scan of deg + block offset -> rowPtr (exclusive), cursor copy
__global__ __launch_bounds__(256) void rowptr_k(const int* __restrict__ deg,
                                                const int* __restrict__ bsumEx,
                                                int* __restrict__ rowPtr,
                                                int* __restrict__ cursor) {
  __shared__ int a[256], b[256];
  int t = threadIdx.x;
  int i = blockIdx.x * 256 + t;
  int d = deg[i];
  a[t] = d;
  __syncthreads();
  int* in = a;
  int* out = b;
  for (int st = 1; st < 256; st <<= 1) {
    out[t] = in[t] + (t >= st ? in[t - st] : 0);
    __syncthreads();
    int* tmp = in; in = out; out = tmp;
  }
  int incl = in[t] + bsumEx[blockIdx.x];
  rowPtr[i + 1] = incl;
  cursor[i] = incl - d;
  if (i == 0) rowPtr[0] = 0;
}

// ---- dst-partitioned CSR fill (8 part-groups; kills cross-XCD csr line thrash) ----
__global__ __launch_bounds__(256) void fill_part_k(const int* __restrict__ src,
                                                   const int* __restrict__ dst,
                                                   int* __restrict__ cursor,
                                                   int* __restrict__ csr,
                                                   int E, int N) {
  const int part = blockIdx.x & 7;
  const int bid = blockIdx.x >> 3;
  const int nblk = gridDim.x >> 3;
  const int nlo = part * (N >> 3);
  const int nhi = nlo + (N >> 3);
  for (int e = bid * 256 + threadIdx.x; e < E; e += nblk * 256) {
    int d = dst[e];
    if (d >= nlo && d < nhi) {
      int p = atomicAdd(cursor + d, 1);
      csr[p] = src[e];
    }
  }
}

// ---- GEMM with LDS-staged x tile. 32 nodes/block, 4 waves x 8 nodes.
// out1 = fp8_e4m3(x @ W1.T) ; DUAL: out2 = fp32(bias2 + x @ W2.T)
template <int K, int DUAL>
__global__ __launch_bounds__(256) void gemm_k(const float4* __restrict__ x4,
                                              const float4* __restrict__ wt1,
                                              const float4* __restrict__ wt2,
                                              const float* __restrict__ bias2,
                                              unsigned char* __restrict__ out1,
                                              float* __restrict__ out2) {
  constexpr int K4 = K / 4;
  __shared__ float4 sx[32 * K4];
  const int t = threadIdx.x;
  const int nb = blockIdx.x * 32;
#pragma unroll
  for (int idx = t; idx < 32 * K4; idx += 256) sx[idx] = x4[(size_t)nb * K4 + idx];
  __syncthreads();
  const int j = t & 63;
  const int wv = t >> 6;
  const int r0 = wv * 8;
  float acc1[8], acc2[8];
  const float bj = DUAL ? bias2[j] : 0.0f;
#pragma unroll
  for (int i = 0; i < 8; i++) { acc1[i] = 0.0f; acc2[i] = bj; }
  for (int k4 = 0; k4 < K4; k4++) {
    float4 w1 = wt1[k4 * 64 + j];
    float4 w2;
    if (DUAL) w2 = wt2[k4 * 64 + j];
#pragma unroll
    for (int i = 0; i < 8; i++) {
      float4 xv = sx[(r0 + i) * K4 + k4];   // broadcast ds_read_b128
      acc1[i] += xv.x * w1.x + xv.y * w1.y + xv.z * w1.z + xv.w * w1.w;
      if (DUAL)
        acc2[i] += xv.x * w2.x + xv.y * w2.y + xv.z * w2.z + xv.w * w2.w;
    }
  }
#pragma unroll
  for (int i = 0; i < 8; i++) {
    // OCP e4m3 encode (gfx950 v_cvt_pk_fp8_f32, RNE, saturating)
    unsigned pk = (unsigned)__builtin_amdgcn_cvt_pk_fp8_f32(acc1[i], acc1[i], 0, false);
    out1[(size_t)(nb + r0 + i) * 64 + j] = (unsigned char)(pk & 0xff);
    if (DUAL) out2[(size_t)(nb + r0 + i) * 64 + j] = acc2[i];
  }
}

// ---- gather aggregation over fp8 messages, fused graph-mean accumulation ----
// MLP-first design: 4 lanes/edge x uint4 (16 fp8, 16 B) -> 16 edges IN FLIGHT per
// wave instruction (round 7 showed gather is latency-bound at ~1 outstanding
// line/wave; this raises it 16x). Row = 64 B = one cache line per edge.
// Edge ids read directly (csr[e], HW broadcast within the 4-lane group) — NO shfl
// of edge ids (undefined from exited lanes; caused round-2/4 failures).
// WRITE_H=1: hio[n] = sum*invdeg + hio[n] (in-place fp32), gmean += h/2048
// WRITE_H=0: gmean += (sum*invdeg)/2048  (h2 never materialized)
template <int WRITE_H>
__global__ __launch_bounds__(256) void gather_k(const uint4* __restrict__ yb,
                                                const int* __restrict__ csr,
                                                const int* __restrict__ rowPtr,
                                                const float* __restrict__ invdeg,
                                                float4* __restrict__ hio,
                                                float* __restrict__ gmean) {
  __shared__ float sg[4][4][16];
  const int t = threadIdx.x;
  const int lane = t & 63;
  const int wv = t >> 6;
  const int q = lane & 3;    // 16-byte quarter of the 64-B row (elements q*16..q*16+15)
  const int eg = lane >> 2;  // edge group 0..15
  const int nb = blockIdx.x * 16;  // 16 consecutive nodes/block (2048%16==0 -> same graph)
  float gacc[16];
#pragma unroll
  for (int k = 0; k < 16; k++) gacc[k] = 0.0f;
  const int n0 = nb + wv * 4;
  int rp[5];
#pragma unroll
  for (int k = 0; k < 5; k++) rp[k] = rowPtr[n0 + k];   // prefetched, broadcast
  for (int i = 0; i < 4; i++) {
    int n = n0 + i;
    int base = rp[i], end = rp[i + 1];
    float acc[16];
#pragma unroll
    for (int k = 0; k < 16; k++) acc[k] = 0.0f;
    for (int e = base + eg; e < end; e += 16) {
      int s = csr[e];
      uint4 v = yb[(size_t)s * 4 + q];
      f32x2 p;
      p = __builtin_amdgcn_cvt_pk_f32_fp8(v.x, false); acc[0] += p.x;  acc[1] += p.y;
      p = __builtin_amdgcn_cvt_pk_f32_fp8(v.x, true);  acc[2] += p.x;  acc[3] += p.y;
      p = __builtin_amdgcn_cvt_pk_f32_fp8(v.y, false); acc[4] += p.x;  acc[5] += p.y;
      p = __builtin_amdgcn_cvt_pk_f32_fp8(v.y, true);  acc[6] += p.x;  acc[7] += p.y;
      p = __builtin_amdgcn_cvt_pk_f32_fp8(v.z, false); acc[8] += p.x;  acc[9] += p.y;
      p = __builtin_amdgcn_cvt_pk_f32_fp8(v.z, true);  acc[10] += p.x; acc[11] += p.y;
      p = __builtin_amdgcn_cvt_pk_f32_fp8(v.w, false); acc[12] += p.x; acc[13] += p.y;
      p = __builtin_amdgcn_cvt_pk_f32_fp8(v.w, true);  acc[14] += p.x; acc[15] += p.y;
    }
    // reduce across the 16 edge groups (lane bits 2..5)
#pragma unroll
    for (int m = 4; m <= 32; m <<= 1)
#pragma unroll
      for (int k = 0; k < 16; k++) acc[k] += __shfl_xor(acc[k], m, 64);
    if (eg == 0) {   // lanes 0..3 hold the full row sum (lane q: elems q*16..q*16+15)
      float sc = invdeg[n];
      if (WRITE_H) {
#pragma unroll
        for (int u = 0; u < 4; u++) {
          float4 o = hio[(size_t)n * 16 + 4 * q + u];
          float4 h = make_float4(acc[4 * u + 0] * sc + o.x, acc[4 * u + 1] * sc + o.y,
                                 acc[4 * u + 2] * sc + o.z, acc[4 * u + 3] * sc + o.w);
          hio[(size_t)n * 16 + 4 * q + u] = h;
          gacc[4 * u + 0] += h.x; gacc[4 * u + 1] += h.y;
          gacc[4 * u + 2] += h.z; gacc[4 * u + 3] += h.w;
        }
      } else {
#pragma unroll
        for (int k = 0; k < 16; k++) gacc[k] += acc[k] * sc;
      }
    }
  }
  if (eg == 0) {
#pragma unroll
    for (int k = 0; k < 16; k++) sg[wv][q][k] = gacc[k];
  }
  __syncthreads();
  if (t < 64) {   // element j = t = q*16 + k
    int qq = t >> 4, k = t & 15;
    float tot = sg[0][qq][k] + sg[1][qq][k] + sg[2][qq][k] + sg[3][qq][k];
    atomicAdd(gmean + (nb >> 11) * 64 + t, tot * (1.0f / 2048.0f));
  }
}

// ---- g[b][j] = gmean2[b][j] + b2l[j] + sum_k gmean1[b][k] * W2r[j][k] ----
__global__ __launch_bounds__(256) void combine_k(const float* __restrict__ gmean2,
                                                 const float* __restrict__ gmean1,
                                                 const float* __restrict__ b2l,
                                                 const float* __restrict__ W2r,
                                                 float* __restrict__ g) {
  int idx = blockIdx.x * 256 + threadIdx.x;   // 4096
  int b = idx >> 6, j = idx & 63;
  const float4* m4 = (const float4*)(gmean1 + b * 64);
  const float4* w4 = (const float4*)(W2r + j * 64);
  float acc = gmean2[idx] + b2l[j];
#pragma unroll
  for (int k4 = 0; k4 < 16; k4++) {
    float4 mv = m4[k4], wv = w4[k4];
    acc += mv.x * wv.x + mv.y * wv.y + mv.z * wv.z + mv.w * wv.w;
  }
  g[idx] = acc;
}

// ---- h = relu(g @ fc1_W.T + fc1_b)   g:[64,64] fc1_W:[128,64] -> h:[64,128] ----
__global__ __launch_bounds__(256) void mlp1_k(const float* __restrict__ g,
                                              const float* __restrict__ fc1_W,
                                              const float* __restrict__ fc1_b,
                                              float* __restrict__ h) {
  int idx = blockIdx.x * 256 + threadIdx.x;
  int b = idx >> 7, k = idx & 127;
  const float4* g4 = (const float4*)(g + b * 64);
  const float4* w4 = (const float4*)(fc1_W + k * 64);
  float acc = fc1_b[k];
#pragma unroll
  for (int j4 = 0; j4 < 16; j4++) {
    float4 gv = g4[j4], wv = w4[j4];
    acc += gv.x * wv.x + gv.y * wv.y + gv.z * wv.z + gv.w * wv.w;
  }
  h[idx] = fmaxf(acc, 0.0f);
}

// ---- q = h @ fc2_W.T + fc2_b   h:[64,128] fc2_W:[2048,128] -> q:[64,2048] ----
__global__ __launch_bounds__(256) void mlp2_k(const float* __restrict__ h,
                                              const float* __restrict__ fc2_W,
                                              const float* __restrict__ fc2_b,
                                              float* __restrict__ out) {
  __shared__ float4 sh[32];
  int b = blockIdx.x >> 3;
  int a = (blockIdx.x & 7) * 256 + threadIdx.x;
  if (threadIdx.x < 32) sh[threadIdx.x] = ((const float4*)(h + b * 128))[threadIdx.x];
  __syncthreads();
  const float4* w4 = (const float4*)(fc2_W + (size_t)a * 128);
  float acc = fc2_b[a];
#pragma unroll
  for (int k4 = 0; k4 < 32; k4++) {
    float4 hv = sh[k4], wv = w4[k4];
    acc += hv.x * wv.x + hv.y * wv.y + hv.z * wv.z + hv.w * wv.w;
  }
  out[b * 2048 + a] = acc;
}

extern "C" void kernel_launch(void* const* d_in, const int* in_sizes, int n_in,
                              void* d_out, int out_size, void* d_ws, size_t ws_size,
                              hipStream_t stream) {
  const float* x     = (const float*)d_in[0];
  const int*   ei    = (const int*)d_in[1];
  const float* W1l   = (const float*)d_in[2];
  const float* b1l   = (const float*)d_in[3];
  const float* W1r   = (const float*)d_in[4];
  const float* W2l   = (const float*)d_in[5];
  const float* b2l   = (const float*)d_in[6];
  const float* W2r   = (const float*)d_in[7];
  const float* fc1_W = (const float*)d_in[8];
  const float* fc1_b = (const float*)d_in[9];
  const float* fc2_W = (const float*)d_in[10];
  const float* fc2_b = (const float*)d_in[11];
  float* out = (float*)d_out;

  const int N = in_sizes[0] / D_IN;   // 131072
  const int E = in_sizes[1] / 2;      // 2097152
  const int* src = ei;
  const int* dst = ei + E;

  // workspace layout (~52 MiB total; 78 MiB proven available in round 3)
  char* ws = (char*)d_ws;
  int*   deg    = (int*)ws;     ws += (size_t)N * 4;
  int*   cursor = (int*)ws;     ws += (size_t)N * 4;
  int*   rowPtr = (int*)ws;     ws += (size_t)(N + 256) * 4;
  int*   bsum   = (int*)ws;     ws += 512 * 4;
  float* invdeg = (float*)ws;   ws += (size_t)N * 4;
  float* gmean1 = (float*)ws;   ws += 4096 * 4;
  float* gmean2 = (float*)ws;   ws += 4096 * 4;
  float* g      = (float*)ws;   ws += 4096 * 4;
  float* hbuf   = (float*)ws;   ws += 8192 * 4;
  float* wt1l   = (float*)ws;   ws += 8192 * 4;
  float* wt1r   = (float*)ws;   ws += 8192 * 4;
  float* wt2l   = (float*)ws;   ws += 4096 * 4;
  int*   csr    = (int*)ws;     ws += (size_t)E * 4;
  unsigned char* bufA = (unsigned char*)ws;  ws += (size_t)64 * N;      // y1/y2 fp8
  float* bufB   = (float*)ws;   ws += (size_t)64 * N * 4;  // xr -> h1 (in place, fp32)

  hipMemsetAsync(deg, 0, (size_t)N * 4, stream);
  hipMemsetAsync(gmean1, 0, 2 * 4096 * 4, stream);   // gmean1 + gmean2 contiguous

  wprep_k<<<8, 256, 0, stream>>>((const float4*)W1l, (float4*)wt1l, 32);
  wprep_k<<<8, 256, 0, stream>>>((const float4*)W1r, (float4*)wt1r, 32);
  wprep_k<<<4, 256, 0, stream>>>((const float4*)W2l, (float4*)wt2l, 16);

  // CSR build (reused by both convs)
  degcnt_part_k<<<1024, 256, 0, stream>>>(dst, deg, E, N);
  invdeg_k<<<(N + 255) / 256, 256, 0, stream>>>(deg, invdeg, N);
  blocksum_k<<<N / 256, 256, 0, stream>>>(deg, bsum);
  scanbsum_k<<<1, 256, 0, stream>>>(bsum);
  rowptr_k<<<N / 256, 256, 0, stream>>>(deg, bsum, rowPtr, cursor);
  fill_part_k<<<1024, 256, 0, stream>>>(src, dst, cursor, csr, E, N);

  // conv1: y1 = fp8(x@W1l.T) -> bufA ; xr = b1l + x@W1r.T -> bufB (fp32)
  gemm_k<128, 1><<<N / 32, 256, 0, stream>>>((const float4*)x, (const float4*)wt1l,
                                             (const float4*)wt1r, b1l, bufA, bufB);
  // h1 = gather(y1)*invdeg + xr -> bufB in place; gmean1 += h1/2048
  gather_k<1><<<N / 16, 256, 0, stream>>>((const uint4*)bufA, csr, rowPtr, invdeg,
                                          (float4*)bufB, gmean1);

  // conv2: y2 = fp8(h1@W2l.T) -> bufA
  gemm_k<64, 0><<<N / 32, 256, 0, stream>>>((const float4*)bufB, (const float4*)wt2l,
                                            nullptr, nullptr, bufA, nullptr);
  // gmean2 += gather(y2)*invdeg / 2048  (h2 never materialized)
  gather_k<0><<<N / 16, 256, 0, stream>>>((const uint4*)bufA, csr, rowPtr, invdeg,
                                          nullptr, gmean2);

  // g = gmean2 + b2l + gmean1 @ W2r.T
  combine_k<<<16, 256, 0, stream>>>(gmean2, gmean1, b2l, W2r, g);
  mlp1_k<<<32, 256, 0, stream>>>(g, fc1_W, fc1_b, hbuf);
  mlp2_k<<<512, 256, 0, stream>>>(hbuf, fc2_W, fc2_b, out);
}

// Round 10
// 566.157 us; speedup vs baseline: 1.2965x; 1.0966x over previous
//
#include <hip/hip_runtime.h>
#include <hip/hip_bf16.h>

#define D_IN 128
#define D_EMB 64

typedef float f32x2 __attribute__((ext_vector_type(2)));
typedef float f32x4v __attribute__((ext_vector_type(4)));
typedef short bf16x8 __attribute__((ext_vector_type(8)));   // 8 bf16 = 4 VGPRs (guide §3)

static __device__ __forceinline__ unsigned short f2bf(float f) {
  __hip_bfloat16 h = __float2bfloat16(f);
  return *(unsigned short*)&h;
}

// ---- MFMA weight prep: W[64][K] fp32 -> packed bf16 B-fragments.
// frag index tid=(s*4+ct)*64+lane holds W[ct*16+(lane&15)][s*32+(lane>>4)*8 + j], j=0..7
__global__ __launch_bounds__(256) void wprep_mfma_k(const float* __restrict__ W,
                                                    unsigned short* __restrict__ out,
                                                    int K) {
  int tid = blockIdx.x * 256 + threadIdx.x;
  int total = (K / 32) * 4 * 64;
  if (tid >= total) return;
  int lane = tid & 63;
  int ct = (tid >> 6) & 3;
  int s = tid >> 8;
  int row = ct * 16 + (lane & 15);
  int kk = s * 32 + (lane >> 4) * 8;
  unsigned short tmp[8];
#pragma unroll
  for (int j = 0; j < 8; j++) tmp[j] = f2bf(W[row * K + kk + j]);
  *(uint4*)&out[(size_t)tid * 8] = *(uint4*)tmp;
}

// ---- CSR build ----
// dst-partitioned degree count (cross-XCD line-thrash fix)
__global__ __launch_bounds__(256) void degcnt_part_k(const int* __restrict__ dst,
                                                     int* __restrict__ deg,
                                                     int E, int N) {
  const int part = blockIdx.x & 7;
  const int bid = blockIdx.x >> 3;
  const int nblk = gridDim.x >> 3;
  const int nlo = part * (N >> 3), nhi = nlo + (N >> 3);
  for (int e = bid * 256 + threadIdx.x; e < E; e += nblk * 256) {
    int d = dst[e];
    if (d >= nlo && d < nhi) atomicAdd(deg + d, 1);
  }
}

__global__ __launch_bounds__(256) void invdeg_k(const int* __restrict__ deg,
                                                float* __restrict__ invdeg, int N) {
  int i = blockIdx.x * 256 + threadIdx.x;
  if (i < N) invdeg[i] = 1.0f / fmaxf((float)deg[i], 1.0f);
}

__global__ __launch_bounds__(256) void blocksum_k(const int* __restrict__ deg,
                                                  int* __restrict__ bsum) {
  __shared__ int sm[256];
  int t = threadIdx.x;
  sm[t] = deg[blockIdx.x * 256 + t];
  __syncthreads();
  for (int s = 128; s > 0; s >>= 1) {
    if (t < s) sm[t] += sm[t + s];
    __syncthreads();
  }
  if (t == 0) bsum[blockIdx.x] = sm[0];
}

// single block: exclusive scan of 512 block sums (in place)
__global__ __launch_bounds__(256) void scanbsum_k(int* __restrict__ bsum) {
  __shared__ int a[512], b[512];
  int t = threadIdx.x;
  a[t] = bsum[t];
  a[t + 256] = bsum[t + 256];
  __syncthreads();
  int* in = a;
  int* out = b;
  for (int st = 1; st < 512; st <<= 1) {
    for (int i = t; i < 512; i += 256) out[i] = in[i] + (i >= st ? in[i - st] : 0);
    __syncthreads();
    int* tmp = in; in = out; out = tmp;
  }
  for (int i = t; i < 512; i += 256) bsum[i] = (i == 0) ? 0 : in[i - 1];
}

// per-block inclusive scan of deg + block offset -> rowPtr (exclusive), cursor copy
__global__ __launch_bounds__(256) void rowptr_k(const int* __restrict__ deg,
                                                const int* __restrict__ bsumEx,
                                                int* __restrict__ rowPtr,
                                                int* __restrict__ cursor) {
  __shared__ int a[256], b[256];
  int t = threadIdx.x;
  int i = blockIdx.x * 256 + t;
  int d = deg[i];
  a[t] = d;
  __syncthreads();
  int* in = a;
  int* out = b;
  for (int st = 1; st < 256; st <<= 1) {
    out[t] = in[t] + (t >= st ? in[t - st] : 0);
    __syncthreads();
    int* tmp = in; in = out; out = tmp;
  }
  int incl = in[t] + bsumEx[blockIdx.x];
  rowPtr[i + 1] = incl;
  cursor[i] = incl - d;
  if (i == 0) rowPtr[0] = 0;
}

// ---- dst-partitioned CSR fill (8 part-groups; kills cross-XCD csr line thrash) ----
__global__ __launch_bounds__(256) void fill_part_k(const int* __restrict__ src,
                                                   const int* __restrict__ dst,
                                                   int* __restrict__ cursor,
                                                   int* __restrict__ csr,
                                                   int E, int N) {
  const int part = blockIdx.x & 7;
  const int bid = blockIdx.x >> 3;
  const int nblk = gridDim.x >> 3;
  const int nlo = part * (N >> 3);
  const int nhi = nlo + (N >> 3);
  for (int e = bid * 256 + threadIdx.x; e < E; e += nblk * 256) {
    int d = dst[e];
    if (d >= nlo && d < nhi) {
      int p = atomicAdd(cursor + d, 1);
      csr[p] = src[e];
    }
  }
}

// ---- MFMA GEMM: 64 nodes/block, 4 waves x 16-node tile, 16x16x32 bf16 MFMA.
// out1 = fp8_e4m3(x @ W1.T) ; DUAL: out2 = fp32(bias2 + x @ W2.T)
// A-frag: A[m=lane&15][k=quad*8+j] (guide-verified). B pre-packed by wprep_mfma_k.
// C/D: col=lane&15, row=quad*4+reg (m89-verified).
template <int K, int DUAL>
__global__ __launch_bounds__(256) void gemm_mfma_k(const float4* __restrict__ x4,
                                                   const unsigned short* __restrict__ wb1,
                                                   const unsigned short* __restrict__ wb2,
                                                   const float* __restrict__ bias2,
                                                   unsigned char* __restrict__ out1,
                                                   float* __restrict__ out2) {
  constexpr int K4 = K / 4;
  constexpr int LROW = K + 8;   // pad 8 bf16 (16 B) to break fragment-read bank conflicts
  __shared__ unsigned short sxb[64 * LROW];
  const int t = threadIdx.x;
  const int nb = blockIdx.x * 64;
  // stage x (fp32) -> LDS bf16, coalesced float4 reads
#pragma unroll
  for (int idx = t; idx < 64 * K4; idx += 256) {
    int node = idx / K4, k4 = idx - node * K4;
    float4 v = x4[(size_t)(nb + node) * K4 + k4];
    ushort4 h;
    h.x = f2bf(v.x); h.y = f2bf(v.y); h.z = f2bf(v.z); h.w = f2bf(v.w);
    *(ushort4*)&sxb[node * LROW + k4 * 4] = h;
  }
  __syncthreads();
  const int lane = t & 63;
  const int wv = t >> 6;
  const int col = lane & 15;
  const int quad = lane >> 4;
  f32x4v acc1[4], acc2[4];
#pragma unroll
  for (int ct = 0; ct < 4; ct++) {
    acc1[ct] = (f32x4v){0.f, 0.f, 0.f, 0.f};
    if (DUAL) {
      float bj = bias2[ct * 16 + col];
      acc2[ct] = (f32x4v){bj, bj, bj, bj};
    }
  }
#pragma unroll
  for (int s = 0; s < K / 32; s++) {
    bf16x8 a = *(const bf16x8*)&sxb[(wv * 16 + col) * LROW + s * 32 + quad * 8];
#pragma unroll
    for (int ct = 0; ct < 4; ct++) {
      bf16x8 b1 = *(const bf16x8*)&wb1[(size_t)((s * 4 + ct) * 64 + lane) * 8];
      acc1[ct] = __builtin_amdgcn_mfma_f32_16x16x32_bf16(a, b1, acc1[ct], 0, 0, 0);
      if (DUAL) {
        bf16x8 b2 = *(const bf16x8*)&wb2[(size_t)((s * 4 + ct) * 64 + lane) * 8];
        acc2[ct] = __builtin_amdgcn_mfma_f32_16x16x32_bf16(a, b2, acc2[ct], 0, 0, 0);
      }
    }
  }
#pragma unroll
  for (int ct = 0; ct < 4; ct++) {
#pragma unroll
    for (int reg = 0; reg < 4; reg++) {
      int node = nb + wv * 16 + quad * 4 + reg;
      unsigned pk = (unsigned)__builtin_amdgcn_cvt_pk_fp8_f32(acc1[ct][reg],
                                                              acc1[ct][reg], 0, false);
      out1[(size_t)node * 64 + ct * 16 + col] = (unsigned char)(pk & 0xff);
      if (DUAL) out2[(size_t)node * 64 + ct * 16 + col] = acc2[ct][reg];
    }
  }
}

// ---- gather aggregation over fp8 messages ----
// 4 lanes/edge x uint4 (16 fp8) -> 16 edges in flight per wave (latency-bound fix, r8).
// Edge ids read directly (csr[e], HW broadcast) — NO shfl of edge ids.
// Graph-mean contribution written as DETERMINISTIC per-block partials (no atomics):
// pm[graph][blk_in_graph][64], reduced later in fixed order by reduce_part_k.
template <int WRITE_H>
__global__ __launch_bounds__(256) void gather_k(const uint4* __restrict__ yb,
                                                const int* __restrict__ csr,
                                                const int* __restrict__ rowPtr,
                                                const float* __restrict__ invdeg,
                                                float4* __restrict__ hio,
                                                float* __restrict__ pm) {
  __shared__ float sg[4][4][16];
  const int t = threadIdx.x;
  const int lane = t & 63;
  const int wv = t >> 6;
  const int q = lane & 3;    // 16-byte quarter of the 64-B row
  const int eg = lane >> 2;  // edge group 0..15
  const int nb = blockIdx.x * 16;
  float gacc[16];
#pragma unroll
  for (int k = 0; k < 16; k++) gacc[k] = 0.0f;
  const int n0 = nb + wv * 4;
  int rp[5];
#pragma unroll
  for (int k = 0; k < 5; k++) rp[k] = rowPtr[n0 + k];
  for (int i = 0; i < 4; i++) {
    int n = n0 + i;
    int base = rp[i], end = rp[i + 1];
    float acc[16];
#pragma unroll
    for (int k = 0; k < 16; k++) acc[k] = 0.0f;
    for (int e = base + eg; e < end; e += 16) {
      int s = csr[e];
      uint4 v = yb[(size_t)s * 4 + q];
      f32x2 p;
      p = __builtin_amdgcn_cvt_pk_f32_fp8(v.x, false); acc[0] += p.x;  acc[1] += p.y;
      p = __builtin_amdgcn_cvt_pk_f32_fp8(v.x, true);  acc[2] += p.x;  acc[3] += p.y;
      p = __builtin_amdgcn_cvt_pk_f32_fp8(v.y, false); acc[4] += p.x;  acc[5] += p.y;
      p = __builtin_amdgcn_cvt_pk_f32_fp8(v.y, true);  acc[6] += p.x;  acc[7] += p.y;
      p = __builtin_amdgcn_cvt_pk_f32_fp8(v.z, false); acc[8] += p.x;  acc[9] += p.y;
      p = __builtin_amdgcn_cvt_pk_f32_fp8(v.z, true);  acc[10] += p.x; acc[11] += p.y;
      p = __builtin_amdgcn_cvt_pk_f32_fp8(v.w, false); acc[12] += p.x; acc[13] += p.y;
      p = __builtin_amdgcn_cvt_pk_f32_fp8(v.w, true);  acc[14] += p.x; acc[15] += p.y;
    }
#pragma unroll
    for (int m = 4; m <= 32; m <<= 1)
#pragma unroll
      for (int k = 0; k < 16; k++) acc[k] += __shfl_xor(acc[k], m, 64);
    if (eg == 0) {
      float sc = invdeg[n];
      if (WRITE_H) {
#pragma unroll
        for (int u = 0; u < 4; u++) {
          float4 o = hio[(size_t)n * 16 + 4 * q + u];
          float4 h = make_float4(acc[4 * u + 0] * sc + o.x, acc[4 * u + 1] * sc + o.y,
                                 acc[4 * u + 2] * sc + o.z, acc[4 * u + 3] * sc + o.w);
          hio[(size_t)n * 16 + 4 * q + u] = h;
          gacc[4 * u + 0] += h.x; gacc[4 * u + 1] += h.y;
          gacc[4 * u + 2] += h.z; gacc[4 * u + 3] += h.w;
        }
      } else {
#pragma unroll
        for (int k = 0; k < 16; k++) gacc[k] += acc[k] * sc;
      }
    }
  }
  if (eg == 0) {
#pragma unroll
    for (int k = 0; k < 16; k++) sg[wv][q][k] = gacc[k];
  }
  __syncthreads();
  if (t < 64) {
    int qq = t >> 4, k = t & 15;
    float tot = sg[0][qq][k] + sg[1][qq][k] + sg[2][qq][k] + sg[3][qq][k];
    int graph = nb >> 11;
    int blkin = blockIdx.x & 127;   // 128 blocks per graph (2048/16)
    pm[((size_t)graph * 128 + blkin) * 64 + t] = tot;   // plain store, deterministic
  }
}

// ---- deterministic partial reduce: gm[b][j] = (1/2048) * sum_blk pm[b][blk][j] ----
__global__ __launch_bounds__(256) void reduce_part_k(const float* __restrict__ pm,
                                                     float* __restrict__ gm) {
  int idx = blockIdx.x * 256 + threadIdx.x;   // 4096
  int b = idx >> 6, j = idx & 63;
  float acc = 0.0f;
  for (int blk = 0; blk < 128; blk++) acc += pm[((size_t)b * 128 + blk) * 64 + j];
  gm[idx] = acc * (1.0f / 2048.0f);
}

// ---- g[b][j] = gmean2[b][j] + b2l[j] + sum_k gmean1[b][k] * W2r[j][k] ----
__global__ __launch_bounds__(256) void combine_k(const float* __restrict__ gmean2,
                                                 const float* __restrict__ gmean1,
                                                 const float* __restrict__ b2l,
                                                 const float* __restrict__ W2r,
                                                 float* __restrict__ g) {
  int idx = blockIdx.x * 256 + threadIdx.x;   // 4096
  int b = idx >> 6, j = idx & 63;
  const float4* m4 = (const float4*)(gmean1 + b * 64);
  const float4* w4 = (const float4*)(W2r + j * 64);
  float acc = gmean2[idx] + b2l[j];
#pragma unroll
  for (int k4 = 0; k4 < 16; k4++) {
    float4 mv = m4[k4], wv = w4[k4];
    acc += mv.x * wv.x + mv.y * wv.y + mv.z * wv.z + mv.w * wv.w;
  }
  g[idx] = acc;
}

// ---- h = relu(g @ fc1_W.T + fc1_b)   g:[64,64] fc1_W:[128,64] -> h:[64,128] ----
__global__ __launch_bounds__(256) void mlp1_k(const float* __restrict__ g,
                                              const float* __restrict__ fc1_W,
                                              const float* __restrict__ fc1_b,
                                              float* __restrict__ h) {
  int idx = blockIdx.x * 256 + threadIdx.x;
  int b = idx >> 7, k = idx & 127;
  const float4* g4 = (const float4*)(g + b * 64);
  const float4* w4 = (const float4*)(fc1_W + k * 64);
  float acc = fc1_b[k];
#pragma unroll
  for (int j4 = 0; j4 < 16; j4++) {
    float4 gv = g4[j4], wv = w4[j4];
    acc += gv.x * wv.x + gv.y * wv.y + gv.z * wv.z + gv.w * wv.w;
  }
  h[idx] = fmaxf(acc, 0.0f);
}

// ---- q = h @ fc2_W.T + fc2_b   h:[64,128] fc2_W:[2048,128] -> q:[64,2048] ----
__global__ __launch_bounds__(256) void mlp2_k(const float* __restrict__ h,
                                              const float* __restrict__ fc2_W,
                                              const float* __restrict__ fc2_b,
                                              float* __restrict__ out) {
  __shared__ float4 sh[32];
  int b = blockIdx.x >> 3;
  int a = (blockIdx.x & 7) * 256 + threadIdx.x;
  if (threadIdx.x < 32) sh[threadIdx.x] = ((const float4*)(h + b * 128))[threadIdx.x];
  __syncthreads();
  const float4* w4 = (const float4*)(fc2_W + (size_t)a * 128);
  float acc = fc2_b[a];
#pragma unroll
  for (int k4 = 0; k4 < 32; k4++) {
    float4 hv = sh[k4], wv = w4[k4];
    acc += hv.x * wv.x + hv.y * wv.y + hv.z * wv.z + hv.w * wv.w;
  }
  out[b * 2048 + a] = acc;
}

extern "C" void kernel_launch(void* const* d_in, const int* in_sizes, int n_in,
                              void* d_out, int out_size, void* d_ws, size_t ws_size,
                              hipStream_t stream) {
  const float* x     = (const float*)d_in[0];
  const int*   ei    = (const int*)d_in[1];
  const float* W1l   = (const float*)d_in[2];
  const float* b1l   = (const float*)d_in[3];
  const float* W1r   = (const float*)d_in[4];
  const float* W2l   = (const float*)d_in[5];
  const float* b2l   = (const float*)d_in[6];
  const float* W2r   = (const float*)d_in[7];
  const float* fc1_W = (const float*)d_in[8];
  const float* fc1_b = (const float*)d_in[9];
  const float* fc2_W = (const float*)d_in[10];
  const float* fc2_b = (const float*)d_in[11];
  float* out = (float*)d_out;

  const int N = in_sizes[0] / D_IN;   // 131072
  const int E = in_sizes[1] / 2;      // 2097152
  const int* src = ei;
  const int* dst = ei + E;

  // workspace layout (~55 MiB; 78 MiB proven available in round 3)
  char* ws = (char*)d_ws;
  int*   deg    = (int*)ws;     ws += (size_t)N * 4;
  int*   cursor = (int*)ws;     ws += (size_t)N * 4;
  int*   rowPtr = (int*)ws;     ws += (size_t)(N + 256) * 4;
  int*   bsum   = (int*)ws;     ws += 512 * 4;
  float* invdeg = (float*)ws;   ws += (size_t)N * 4;
  float* gmean1 = (float*)ws;   ws += 4096 * 4;
  float* gmean2 = (float*)ws;   ws += 4096 * 4;
  float* g      = (float*)ws;   ws += 4096 * 4;
  float* hbuf   = (float*)ws;   ws += 8192 * 4;
  unsigned short* wb1l = (unsigned short*)ws;  ws += 8192 * 2;  // mfma-packed bf16
  unsigned short* wb1r = (unsigned short*)ws;  ws += 8192 * 2;
  unsigned short* wb2l = (unsigned short*)ws;  ws += 4096 * 2;
  float* p1     = (float*)ws;   ws += (size_t)64 * 128 * 64 * 4;  // graph-mean partials
  float* p2     = (float*)ws;   ws += (size_t)64 * 128 * 64 * 4;
  int*   csr    = (int*)ws;     ws += (size_t)E * 4;
  unsigned char* bufA = (unsigned char*)ws;  ws += (size_t)64 * N;      // y1/y2 fp8
  float* bufB   = (float*)ws;   ws += (size_t)64 * N * 4;  // xr -> h1 (in place, fp32)
  size_t used = (size_t)(ws - (char*)d_ws);

  // Zero the ENTIRE used workspace every call. Round 9 passed first validation
  // (unknown initial ws) but diverged on all post-capture runs (ws poisoned 0xAA)
  // -> make every call start from the identical, validated-benign state.
  hipMemsetAsync(d_ws, 0, used, stream);

  wprep_mfma_k<<<4, 256, 0, stream>>>(W1l, wb1l, 128);
  wprep_mfma_k<<<4, 256, 0, stream>>>(W1r, wb1r, 128);
  wprep_mfma_k<<<2, 256, 0, stream>>>(W2l, wb2l, 64);

  // CSR build (reused by both convs)
  degcnt_part_k<<<1024, 256, 0, stream>>>(dst, deg, E, N);
  invdeg_k<<<(N + 255) / 256, 256, 0, stream>>>(deg, invdeg, N);
  blocksum_k<<<N / 256, 256, 0, stream>>>(deg, bsum);
  scanbsum_k<<<1, 256, 0, stream>>>(bsum);
  rowptr_k<<<N / 256, 256, 0, stream>>>(deg, bsum, rowPtr, cursor);
  fill_part_k<<<1024, 256, 0, stream>>>(src, dst, cursor, csr, E, N);

  // conv1: y1 = fp8(x@W1l.T) -> bufA ; xr = b1l + x@W1r.T -> bufB (fp32)
  gemm_mfma_k<128, 1><<<N / 64, 256, 0, stream>>>((const float4*)x, wb1l, wb1r,
                                                  b1l, bufA, bufB);
  // h1 = gather(y1)*invdeg + xr -> bufB in place; p1 partials
  gather_k<1><<<N / 16, 256, 0, stream>>>((const uint4*)bufA, csr, rowPtr, invdeg,
                                          (float4*)bufB, p1);
  reduce_part_k<<<16, 256, 0, stream>>>(p1, gmean1);

  // conv2: y2 = fp8(h1@W2l.T) -> bufA
  gemm_mfma_k<64, 0><<<N / 64, 256, 0, stream>>>((const float4*)bufB, wb2l, nullptr,
                                                 nullptr, bufA, nullptr);
  // p2 partials of gather(y2)*invdeg  (h2 never materialized)
  gather_k<0><<<N / 16, 256, 0, stream>>>((const uint4*)bufA, csr, rowPtr, invdeg,
                                          nullptr, p2);
  reduce_part_k<<<16, 256, 0, stream>>>(p2, gmean2);

  // g = gmean2 + b2l + gmean1 @ W2r.T
  combine_k<<<16, 256, 0, stream>>>(gmean2, gmean1, b2l, W2r, g);
  mlp1_k<<<32, 256, 0, stream>>>(g, fc1_W, fc1_b, hbuf);
  mlp2_k<<<512, 256, 0, stream>>>(hbuf, fc2_W, fc2_b, out);
}

// Round 11
// 444.545 us; speedup vs baseline: 1.6512x; 1.2736x over previous
//
#include <hip/hip_runtime.h>
#include <hip/hip_bf16.h>

#define D_IN 128
#define D_EMB 64

typedef float f32x2 __attribute__((ext_vector_type(2)));
typedef float f32x4v __attribute__((ext_vector_type(4)));
typedef short bf16x8 __attribute__((ext_vector_type(8)));   // 8 bf16 = 4 VGPRs (guide §3)

static __device__ __forceinline__ unsigned short f2bf(float f) {
  __hip_bfloat16 h = __float2bfloat16(f);
  return *(unsigned short*)&h;
}

// ---- MFMA weight prep: W[64][K] fp32 -> packed bf16 B-fragments.
// frag index tid=(s*4+ct)*64+lane holds W[ct*16+(lane&15)][s*32+(lane>>4)*8 + j], j=0..7
__global__ __launch_bounds__(256) void wprep_mfma_k(const float* __restrict__ W,
                                                    unsigned short* __restrict__ out,
                                                    int K) {
  int tid = blockIdx.x * 256 + threadIdx.x;
  int total = (K / 32) * 4 * 64;
  if (tid >= total) return;
  int lane = tid & 63;
  int ct = (tid >> 6) & 3;
  int s = tid >> 8;
  int row = ct * 16 + (lane & 15);
  int kk = s * 32 + (lane >> 4) * 8;
  unsigned short tmp[8];
#pragma unroll
  for (int j = 0; j < 8; j++) tmp[j] = f2bf(W[row * K + kk + j]);
  *(uint4*)&out[(size_t)tid * 8] = *(uint4*)tmp;
}

// ---- CSR build ----
// dst-partitioned degree count (cross-XCD line-thrash fix)
__global__ __launch_bounds__(256) void degcnt_part_k(const int* __restrict__ dst,
                                                     int* __restrict__ deg,
                                                     int E, int N) {
  const int part = blockIdx.x & 7;
  const int bid = blockIdx.x >> 3;
  const int nblk = gridDim.x >> 3;
  const int nlo = part * (N >> 3), nhi = nlo + (N >> 3);
  for (int e = bid * 256 + threadIdx.x; e < E; e += nblk * 256) {
    int d = dst[e];
    if (d >= nlo && d < nhi) atomicAdd(deg + d, 1);
  }
}

__global__ __launch_bounds__(256) void blocksum_k(const int* __restrict__ deg,
                                                  int* __restrict__ bsum) {
  __shared__ int sm[256];
  int t = threadIdx.x;
  sm[t] = deg[blockIdx.x * 256 + t];
  __syncthreads();
  for (int s = 128; s > 0; s >>= 1) {
    if (t < s) sm[t] += sm[t + s];
    __syncthreads();
  }
  if (t == 0) bsum[blockIdx.x] = sm[0];
}

// single block: exclusive scan of 512 block sums (in place)
__global__ __launch_bounds__(256) void scanbsum_k(int* __restrict__ bsum) {
  __shared__ int a[512], b[512];
  int t = threadIdx.x;
  a[t] = bsum[t];
  a[t + 256] = bsum[t + 256];
  __syncthreads();
  int* in = a;
  int* out = b;
  for (int st = 1; st < 512; st <<= 1) {
    for (int i = t; i < 512; i += 256) out[i] = in[i] + (i >= st ? in[i - st] : 0);
    __syncthreads();
    int* tmp = in; in = out; out = tmp;
  }
  for (int i = t; i < 512; i += 256) bsum[i] = (i == 0) ? 0 : in[i - 1];
}

// per-block inclusive scan of deg + block offset -> rowPtr (exclusive), cursor copy,
// fused invdeg
__global__ __launch_bounds__(256) void rowptr_k(const int* __restrict__ deg,
                                                const int* __restrict__ bsumEx,
                                                int* __restrict__ rowPtr,
                                                int* __restrict__ cursor,
                                                float* __restrict__ invdeg) {
  __shared__ int a[256], b[256];
  int t = threadIdx.x;
  int i = blockIdx.x * 256 + t;
  int d = deg[i];
  a[t] = d;
  __syncthreads();
  int* in = a;
  int* out = b;
  for (int st = 1; st < 256; st <<= 1) {
    out[t] = in[t] + (t >= st ? in[t - st] : 0);
    __syncthreads();
    int* tmp = in; in = out; out = tmp;
  }
  int incl = in[t] + bsumEx[blockIdx.x];
  rowPtr[i + 1] = incl;
  cursor[i] = incl - d;
  invdeg[i] = 1.0f / fmaxf((float)d, 1.0f);
  if (i == 0) rowPtr[0] = 0;
}

// ---- dst-partitioned CSR fill (8 part-groups; kills cross-XCD csr line thrash) ----
__global__ __launch_bounds__(256) void fill_part_k(const int* __restrict__ src,
                                                   const int* __restrict__ dst,
                                                   int* __restrict__ cursor,
                                                   int* __restrict__ csr,
                                                   int E, int N) {
  const int part = blockIdx.x & 7;
  const int bid = blockIdx.x >> 3;
  const int nblk = gridDim.x >> 3;
  const int nlo = part * (N >> 3);
  const int nhi = nlo + (N >> 3);
  for (int e = bid * 256 + threadIdx.x; e < E; e += nblk * 256) {
    int d = dst[e];
    if (d >= nlo && d < nhi) {
      int p = atomicAdd(cursor + d, 1);
      csr[p] = src[e];
    }
  }
}

// ---- MFMA GEMM: 64 nodes/block, 4 waves x 16-node tile, 16x16x32 bf16 MFMA.
// out1 = fp8_e4m3(x @ W1.T) ; DUAL: out2 = fp32(bias2 + x @ W2.T)
// A-frag: A[m=lane&15][k=quad*8+j] (guide-verified). B pre-packed by wprep_mfma_k.
// C/D: col=lane&15, row=quad*4+reg (m89-verified).
template <int K, int DUAL>
__global__ __launch_bounds__(256) void gemm_mfma_k(const float4* __restrict__ x4,
                                                   const unsigned short* __restrict__ wb1,
                                                   const unsigned short* __restrict__ wb2,
                                                   const float* __restrict__ bias2,
                                                   unsigned char* __restrict__ out1,
                                                   float* __restrict__ out2) {
  constexpr int K4 = K / 4;
  constexpr int LROW = K + 8;   // pad 8 bf16 (16 B) to break fragment-read bank conflicts
  __shared__ unsigned short sxb[64 * LROW];
  const int t = threadIdx.x;
  const int nb = blockIdx.x * 64;
  // stage x (fp32) -> LDS bf16, coalesced float4 reads
#pragma unroll
  for (int idx = t; idx < 64 * K4; idx += 256) {
    int node = idx / K4, k4 = idx - node * K4;
    float4 v = x4[(size_t)(nb + node) * K4 + k4];
    ushort4 h;
    h.x = f2bf(v.x); h.y = f2bf(v.y); h.z = f2bf(v.z); h.w = f2bf(v.w);
    *(ushort4*)&sxb[node * LROW + k4 * 4] = h;
  }
  __syncthreads();
  const int lane = t & 63;
  const int wv = t >> 6;
  const int col = lane & 15;
  const int quad = lane >> 4;
  f32x4v acc1[4], acc2[4];
#pragma unroll
  for (int ct = 0; ct < 4; ct++) {
    acc1[ct] = (f32x4v){0.f, 0.f, 0.f, 0.f};
    if (DUAL) {
      float bj = bias2[ct * 16 + col];
      acc2[ct] = (f32x4v){bj, bj, bj, bj};
    }
  }
#pragma unroll
  for (int s = 0; s < K / 32; s++) {
    bf16x8 a = *(const bf16x8*)&sxb[(wv * 16 + col) * LROW + s * 32 + quad * 8];
#pragma unroll
    for (int ct = 0; ct < 4; ct++) {
      bf16x8 b1 = *(const bf16x8*)&wb1[(size_t)((s * 4 + ct) * 64 + lane) * 8];
      acc1[ct] = __builtin_amdgcn_mfma_f32_16x16x32_bf16(a, b1, acc1[ct], 0, 0, 0);
      if (DUAL) {
        bf16x8 b2 = *(const bf16x8*)&wb2[(size_t)((s * 4 + ct) * 64 + lane) * 8];
        acc2[ct] = __builtin_amdgcn_mfma_f32_16x16x32_bf16(a, b2, acc2[ct], 0, 0, 0);
      }
    }
  }
#pragma unroll
  for (int ct = 0; ct < 4; ct++) {
#pragma unroll
    for (int reg = 0; reg < 4; reg++) {
      int node = nb + wv * 16 + quad * 4 + reg;
      unsigned pk = (unsigned)__builtin_amdgcn_cvt_pk_fp8_f32(acc1[ct][reg],
                                                              acc1[ct][reg], 0, false);
      out1[(size_t)node * 64 + ct * 16 + col] = (unsigned char)(pk & 0xff);
      if (DUAL) out2[(size_t)node * 64 + ct * 16 + col] = acc2[ct][reg];
    }
  }
}

// ---- gather aggregation over fp8 messages — reduction-free lane mapping ----
// lane = (node, quarter): 64 lanes = 16 nodes x 4 x 16-B quarters. Each lane
// serially sums its own 16-fp8 quarter over the node's edge list: NO cross-lane
// ops on the per-edge path (round-10 profile showed 256 shfl/wave serializing
// the loads). csr reads are linear (L1-hit); consecutive y-loads independent ->
// compiler pipelines several lines in flight per lane (64+ per wave).
// Graph-mean partials: one all-lanes-active shfl tree per wave + LDS, written as
// deterministic per-block partials pm[graph][32][64] (no atomics).
template <int WRITE_H>
__global__ __launch_bounds__(256) void gather_k(const uint4* __restrict__ yb,
                                                const int* __restrict__ csr,
                                                const int* __restrict__ rowPtr,
                                                const float* __restrict__ invdeg,
                                                float4* __restrict__ hio,
                                                float* __restrict__ pm) {
  __shared__ float sg[4][4][16];
  const int t = threadIdx.x;
  const int lane = t & 63;
  const int wv = t >> 6;
  const int q = lane & 3;     // 16-B quarter of the 64-B row
  const int nl = lane >> 2;   // node within wave (0..15)
  const int nb = blockIdx.x * 64;   // 64 nodes per block (4 waves x 16)
  const int n = nb + wv * 16 + nl;
  const int rp0 = rowPtr[n], rp1 = rowPtr[n + 1];
  float acc[16];
#pragma unroll
  for (int k = 0; k < 16; k++) acc[k] = 0.f;
  for (int e = rp0; e < rp1; e++) {
    int s = csr[e];
    uint4 v = yb[(size_t)s * 4 + q];
    f32x2 p;
    p = __builtin_amdgcn_cvt_pk_f32_fp8(v.x, false); acc[0] += p.x;  acc[1] += p.y;
    p = __builtin_amdgcn_cvt_pk_f32_fp8(v.x, true);  acc[2] += p.x;  acc[3] += p.y;
    p = __builtin_amdgcn_cvt_pk_f32_fp8(v.y, false); acc[4] += p.x;  acc[5] += p.y;
    p = __builtin_amdgcn_cvt_pk_f32_fp8(v.y, true);  acc[6] += p.x;  acc[7] += p.y;
    p = __builtin_amdgcn_cvt_pk_f32_fp8(v.z, false); acc[8] += p.x;  acc[9] += p.y;
    p = __builtin_amdgcn_cvt_pk_f32_fp8(v.z, true);  acc[10] += p.x; acc[11] += p.y;
    p = __builtin_amdgcn_cvt_pk_f32_fp8(v.w, false); acc[12] += p.x; acc[13] += p.y;
    p = __builtin_amdgcn_cvt_pk_f32_fp8(v.w, true);  acc[14] += p.x; acc[15] += p.y;
  }
  const float sc = invdeg[n];
  float gacc[16];
  if (WRITE_H) {
#pragma unroll
    for (int u = 0; u < 4; u++) {
      float4 o = hio[(size_t)n * 16 + q * 4 + u];
      float4 h = make_float4(acc[4 * u + 0] * sc + o.x, acc[4 * u + 1] * sc + o.y,
                             acc[4 * u + 2] * sc + o.z, acc[4 * u + 3] * sc + o.w);
      hio[(size_t)n * 16 + q * 4 + u] = h;
      gacc[4 * u + 0] = h.x; gacc[4 * u + 1] = h.y;
      gacc[4 * u + 2] = h.z; gacc[4 * u + 3] = h.w;
    }
  } else {
#pragma unroll
    for (int k = 0; k < 16; k++) gacc[k] = acc[k] * sc;
  }
  // reduce across the wave's 16 nodes (lane bits 2..5) — ALL lanes active, uniform
#pragma unroll
  for (int m = 4; m <= 32; m <<= 1)
#pragma unroll
    for (int k = 0; k < 16; k++) gacc[k] += __shfl_xor(gacc[k], m, 64);
  if (nl == 0) {   // lanes 0..3 hold quarter q's wave sum
#pragma unroll
    for (int k = 0; k < 16; k++) sg[wv][q][k] = gacc[k];
  }
  __syncthreads();
  if (t < 64) {   // element j = t
    int qq = t >> 4, k = t & 15;
    float tot = sg[0][qq][k] + sg[1][qq][k] + sg[2][qq][k] + sg[3][qq][k];
    pm[((size_t)(blockIdx.x >> 5) * 32 + (blockIdx.x & 31)) * 64 + t] = tot;
  }
}

// ---- deterministic partial reduce: gm[b][j] = (1/2048) * sum_blk pm[b][blk][j] ----
__global__ __launch_bounds__(256) void reduce_part_k(const float* __restrict__ pm,
                                                     float* __restrict__ gm) {
  int idx = blockIdx.x * 256 + threadIdx.x;   // 4096
  int b = idx >> 6, j = idx & 63;
  float acc = 0.0f;
  for (int blk = 0; blk < 32; blk++) acc += pm[((size_t)b * 32 + blk) * 64 + j];
  gm[idx] = acc * (1.0f / 2048.0f);
}

// ---- g[b][j] = gmean2[b][j] + b2l[j] + sum_k gmean1[b][k] * W2r[j][k] ----
__global__ __launch_bounds__(256) void combine_k(const float* __restrict__ gmean2,
                                                 const float* __restrict__ gmean1,
                                                 const float* __restrict__ b2l,
                                                 const float* __restrict__ W2r,
                                                 float* __restrict__ g) {
  int idx = blockIdx.x * 256 + threadIdx.x;   // 4096
  int b = idx >> 6, j = idx & 63;
  const float4* m4 = (const float4*)(gmean1 + b * 64);
  const float4* w4 = (const float4*)(W2r + j * 64);
  float acc = gmean2[idx] + b2l[j];
#pragma unroll
  for (int k4 = 0; k4 < 16; k4++) {
    float4 mv = m4[k4], wv = w4[k4];
    acc += mv.x * wv.x + mv.y * wv.y + mv.z * wv.z + mv.w * wv.w;
  }
  g[idx] = acc;
}

// ---- h = relu(g @ fc1_W.T + fc1_b)   g:[64,64] fc1_W:[128,64] -> h:[64,128] ----
__global__ __launch_bounds__(256) void mlp1_k(const float* __restrict__ g,
                                              const float* __restrict__ fc1_W,
                                              const float* __restrict__ fc1_b,
                                              float* __restrict__ h) {
  int idx = blockIdx.x * 256 + threadIdx.x;
  int b = idx >> 7, k = idx & 127;
  const float4* g4 = (const float4*)(g + b * 64);
  const float4* w4 = (const float4*)(fc1_W + k * 64);
  float acc = fc1_b[k];
#pragma unroll
  for (int j4 = 0; j4 < 16; j4++) {
    float4 gv = g4[j4], wv = w4[j4];
    acc += gv.x * wv.x + gv.y * wv.y + gv.z * wv.z + gv.w * wv.w;
  }
  h[idx] = fmaxf(acc, 0.0f);
}

// ---- q = h @ fc2_W.T + fc2_b   h:[64,128] fc2_W:[2048,128] -> q:[64,2048] ----
__global__ __launch_bounds__(256) void mlp2_k(const float* __restrict__ h,
                                              const float* __restrict__ fc2_W,
                                              const float* __restrict__ fc2_b,
                                              float* __restrict__ out) {
  __shared__ float4 sh[32];
  int b = blockIdx.x >> 3;
  int a = (blockIdx.x & 7) * 256 + threadIdx.x;
  if (threadIdx.x < 32) sh[threadIdx.x] = ((const float4*)(h + b * 128))[threadIdx.x];
  __syncthreads();
  const float4* w4 = (const float4*)(fc2_W + (size_t)a * 128);
  float acc = fc2_b[a];
#pragma unroll
  for (int k4 = 0; k4 < 32; k4++) {
    float4 hv = sh[k4], wv = w4[k4];
    acc += hv.x * wv.x + hv.y * wv.y + hv.z * wv.z + hv.w * wv.w;
  }
  out[b * 2048 + a] = acc;
}

extern "C" void kernel_launch(void* const* d_in, const int* in_sizes, int n_in,
                              void* d_out, int out_size, void* d_ws, size_t ws_size,
                              hipStream_t stream) {
  const float* x     = (const float*)d_in[0];
  const int*   ei    = (const int*)d_in[1];
  const float* W1l   = (const float*)d_in[2];
  const float* b1l   = (const float*)d_in[3];
  const float* W1r   = (const float*)d_in[4];
  const float* W2l   = (const float*)d_in[5];
  const float* b2l   = (const float*)d_in[6];
  const float* W2r   = (const float*)d_in[7];
  const float* fc1_W = (const float*)d_in[8];
  const float* fc1_b = (const float*)d_in[9];
  const float* fc2_W = (const float*)d_in[10];
  const float* fc2_b = (const float*)d_in[11];
  float* out = (float*)d_out;

  const int N = in_sizes[0] / D_IN;   // 131072
  const int E = in_sizes[1] / 2;      // 2097152
  const int* src = ei;
  const int* dst = ei + E;

  // workspace layout (~54 MiB; 78 MiB proven available in round 3)
  char* ws = (char*)d_ws;
  int*   deg    = (int*)ws;     ws += (size_t)N * 4;
  int*   cursor = (int*)ws;     ws += (size_t)N * 4;
  int*   rowPtr = (int*)ws;     ws += (size_t)(N + 256) * 4;
  int*   bsum   = (int*)ws;     ws += 512 * 4;
  float* invdeg = (float*)ws;   ws += (size_t)N * 4;
  float* gmean1 = (float*)ws;   ws += 4096 * 4;
  float* gmean2 = (float*)ws;   ws += 4096 * 4;
  float* g      = (float*)ws;   ws += 4096 * 4;
  float* hbuf   = (float*)ws;   ws += 8192 * 4;
  unsigned short* wb1l = (unsigned short*)ws;  ws += 8192 * 2;  // mfma-packed bf16
  unsigned short* wb1r = (unsigned short*)ws;  ws += 8192 * 2;
  unsigned short* wb2l = (unsigned short*)ws;  ws += 4096 * 2;
  float* p1     = (float*)ws;   ws += (size_t)64 * 32 * 64 * 4;  // graph-mean partials
  float* p2     = (float*)ws;   ws += (size_t)64 * 32 * 64 * 4;
  int*   csr    = (int*)ws;     ws += (size_t)E * 4;
  unsigned char* bufA = (unsigned char*)ws;  ws += (size_t)64 * N;      // y1/y2 fp8
  float* bufB   = (float*)ws;   ws += (size_t)64 * N * 4;  // xr -> h1 (in place, fp32)
  size_t used = (size_t)(ws - (char*)d_ws);

  // Zero the ENTIRE used workspace every call (round-10 fix: every call must
  // start from the identical, validated-benign state; ~10 us at HBM write BW).
  hipMemsetAsync(d_ws, 0, used, stream);

  wprep_mfma_k<<<4, 256, 0, stream>>>(W1l, wb1l, 128);
  wprep_mfma_k<<<4, 256, 0, stream>>>(W1r, wb1r, 128);
  wprep_mfma_k<<<2, 256, 0, stream>>>(W2l, wb2l, 64);

  // CSR build (reused by both convs)
  degcnt_part_k<<<1024, 256, 0, stream>>>(dst, deg, E, N);
  blocksum_k<<<N / 256, 256, 0, stream>>>(deg, bsum);
  scanbsum_k<<<1, 256, 0, stream>>>(bsum);
  rowptr_k<<<N / 256, 256, 0, stream>>>(deg, bsum, rowPtr, cursor, invdeg);
  fill_part_k<<<1024, 256, 0, stream>>>(src, dst, cursor, csr, E, N);

  // conv1: y1 = fp8(x@W1l.T) -> bufA ; xr = b1l + x@W1r.T -> bufB (fp32)
  gemm_mfma_k<128, 1><<<N / 64, 256, 0, stream>>>((const float4*)x, wb1l, wb1r,
                                                  b1l, bufA, bufB);
  // h1 = gather(y1)*invdeg + xr -> bufB in place; p1 partials
  gather_k<1><<<N / 64, 256, 0, stream>>>((const uint4*)bufA, csr, rowPtr, invdeg,
                                          (float4*)bufB, p1);
  reduce_part_k<<<16, 256, 0, stream>>>(p1, gmean1);

  // conv2: y2 = fp8(h1@W2l.T) -> bufA
  gemm_mfma_k<64, 0><<<N / 64, 256, 0, stream>>>((const float4*)bufB, wb2l, nullptr,
                                                 nullptr, bufA, nullptr);
  // p2 partials of gather(y2)*invdeg  (h2 never materialized)
  gather_k<0><<<N / 64, 256, 0, stream>>>((const uint4*)bufA, csr, rowPtr, invdeg,
                                          nullptr, p2);
  reduce_part_k<<<16, 256, 0, stream>>>(p2, gmean2);

  // g = gmean2 + b2l + gmean1 @ W2r.T
  combine_k<<<16, 256, 0, stream>>>(gmean2, gmean1, b2l, W2r, g);
  mlp1_k<<<32, 256, 0, stream>>>(g, fc1_W, fc1_b, hbuf);
  mlp2_k<<<512, 256, 0, stream>>>(hbuf, fc2_W, fc2_b, out);
}